// Round 2
// baseline (378.517 us; speedup 1.0000x reference)
//
#include <hip/hip_runtime.h>
#include <stdint.h>

typedef unsigned short ushort_t;
typedef __bf16 bf16x8 __attribute__((ext_vector_type(8)));
typedef float f32x4 __attribute__((ext_vector_type(4)));

#define SEQ   1024
#define DK    64
#define TOPK_N 51
#define RSCALE 1.2f

// workspace element offsets (ushort elements). A aliases QX (QX dead after gemm modes 0-2).
#define OFF_WT  0                          // 4 * 512*512
#define OFF_Q   (4*512*512)                // 64*1024*64
#define OFF_K   (OFF_Q  + 64*1024*64)
#define OFF_V   (OFF_K  + 64*1024*64)
#define OFF_QX  (OFF_V  + 64*1024*64)      // 8192*512 bf16 copy of Query_x
#define OFF_KVX (OFF_QX + 8192*512)        // 8192*512 bf16 copy of KeyandValue_x
#define OFF_A   OFF_QX                     // attn output (bf16), reuses QX

static __device__ __forceinline__ ushort_t f2bf(float f){
  union { float f; unsigned u; } x; x.f = f;
  unsigned r = x.u + 0x7FFFu + ((x.u >> 16) & 1u);   // RNE
  return (ushort_t)(r >> 16);
}
static __device__ __forceinline__ bf16x8 frag16(const ushort_t* p){
  union { uint4 u; bf16x8 b; } x; x.u = *(const uint4*)p; return x.b;
}
// async global->LDS, 16B per lane; lds base wave-uniform (HW adds lane*16)
static __device__ __forceinline__ void gll16(const ushort_t* g, ushort_t* lds){
  __builtin_amdgcn_global_load_lds((const __attribute__((address_space(1))) unsigned*)g,
                                   (__attribute__((address_space(3))) unsigned*)lds,
                                   16, 0, 0);
}

// ---------------------------------------------------------------------------
// Kernel 0: f32 -> bf16 conversion of the two activation tensors
// ---------------------------------------------------------------------------
__global__ __launch_bounds__(256) void cvt_k(const float* qx, const float* kvx, ushort_t* ws){
  const float* src = blockIdx.y ? kvx : qx;
  ushort_t* dst = ws + (blockIdx.y ? OFF_KVX : OFF_QX);
  int i = (blockIdx.x*256 + threadIdx.x) * 8;
  float4 a = *(const float4*)(src + i);
  float4 b = *(const float4*)(src + i + 4);
  union { ushort_t s[8]; uint4 u; } p;
  p.s[0]=f2bf(a.x); p.s[1]=f2bf(a.y); p.s[2]=f2bf(a.z); p.s[3]=f2bf(a.w);
  p.s[4]=f2bf(b.x); p.s[5]=f2bf(b.y); p.s[6]=f2bf(b.z); p.s[7]=f2bf(b.w);
  *(uint4*)(dst + i) = p.u;
}

// ---------------------------------------------------------------------------
// Kernel 1: convert + transpose the four 512x512 f32 weights: WT[n][k] = bf16(W[k][n])
// ---------------------------------------------------------------------------
__global__ __launch_bounds__(256) void wtrans_k(const float* Wq, const float* Wk,
    const float* Wv, const float* Wo, ushort_t* wt){
  __shared__ ushort_t t[64][72];  // +8 pad
  int z = blockIdx.z;
  const float* W = z==0?Wq: z==1?Wk: z==2?Wv: Wo;
  ushort_t* O = wt + (size_t)z*512*512;
  int kt = blockIdx.y*64, nt = blockIdx.x*64;
  int tid = threadIdx.x;
  int r0 = tid>>3, c8 = (tid&7)*8;
  #pragma unroll
  for (int p=0;p<2;p++){
    int r = p*32 + r0;
    float4 a = *(const float4*)&W[(size_t)(kt+r)*512 + nt + c8];
    float4 b = *(const float4*)&W[(size_t)(kt+r)*512 + nt + c8 + 4];
    t[r][c8+0]=f2bf(a.x); t[r][c8+1]=f2bf(a.y); t[r][c8+2]=f2bf(a.z); t[r][c8+3]=f2bf(a.w);
    t[r][c8+4]=f2bf(b.x); t[r][c8+5]=f2bf(b.y); t[r][c8+6]=f2bf(b.z); t[r][c8+7]=f2bf(b.w);
  }
  __syncthreads();
  #pragma unroll
  for (int p=0;p<2;p++){
    int r = p*32 + r0;
    union { ushort_t s[8]; uint4 u; } tmp;
    #pragma unroll
    for (int j=0;j<8;j++) tmp.s[j] = t[c8+j][r];
    *(uint4*)&O[(size_t)(nt+r)*512 + kt + c8] = tmp.u;
  }
}

// ---------------------------------------------------------------------------
// Kernel 2/4: 128x128-tile bf16 GEMM  Y = X*W + b  (W transposed, bf16 in ws).
// mode 0: Q proj (X=QXb)  -> Qs[n][s][64], scaled 1/8 (=1/sqrt(dk))
// mode 1: K proj (X=KVXb) -> Ks[n][s][64]
// mode 2: V proj (X=KVXb) -> Vb[n][sb][d][ss]  (s=sb*8+ss, blocked for PV B-frags)
// mode 3: out proj (X=A)  -> d_out [8192][512] f32
// ---------------------------------------------------------------------------
__global__ __launch_bounds__(256) void gemm_k(ushort_t* ws, const float* bq, const float* bk,
    const float* bv, const float* bo, float* dout, int base_mode){
  int mode = base_mode + blockIdx.z;
  const ushort_t* X  = (mode==0)? ws+OFF_QX : (mode==3)? ws+OFF_A : ws+OFF_KVX;
  const ushort_t* WT = ws + OFF_WT + (size_t)mode*(512*512);
  const float* bias  = (mode==0)?bq:(mode==1)?bk:(mode==2)?bv:bo;
  ushort_t* out = (mode==0)? ws+OFF_Q : (mode==1)? ws+OFF_K : ws+OFF_V;

  __shared__ ushort_t sA[128*64];
  __shared__ ushort_t sB[128*64];
  int tid = threadIdx.x, lane = tid & 63, w = tid >> 6;
  int wm = w & 1, wn = w >> 1;
  int m0 = blockIdx.y * 128, n0 = blockIdx.x * 128;
  int r16 = lane & 15, quad = lane >> 4;
  int srow = lane >> 3, schunk = lane & 7;   // staging: 8 rows x 8 chunks of 16B

  const f32x4 zero = {0.f,0.f,0.f,0.f};
  f32x4 acc[4][4];
  #pragma unroll
  for (int i=0;i<4;i++)
    #pragma unroll
    for (int j=0;j<4;j++) acc[i][j] = zero;

  for (int kb = 0; kb < 8; kb++){
    int k0 = kb*64;
    #pragma unroll
    for (int i=0;i<4;i++){
      int rb = w*32 + i*8;                 // rb % 8 == 0
      int gch = schunk ^ srow;             // xor-swizzle: slot s holds chunk s^(row&7)
      gll16(X  + (size_t)(m0+rb+srow)*512 + k0 + gch*8, sA + rb*64);
      gll16(WT + (size_t)(n0+rb+srow)*512 + k0 + gch*8, sB + rb*64);
    }
    __syncthreads();
    #pragma unroll
    for (int t=0;t<2;t++){
      bf16x8 aF[4], bF[4];
      #pragma unroll
      for (int i=0;i<4;i++){
        int row = wm*64 + i*16 + r16;
        aF[i] = frag16(sA + row*64 + ((t*4 + quad) ^ (row & 7))*8);
      }
      #pragma unroll
      for (int j=0;j<4;j++){
        int row = wn*64 + j*16 + r16;
        bF[j] = frag16(sB + row*64 + ((t*4 + quad) ^ (row & 7))*8);
      }
      #pragma unroll
      for (int i=0;i<4;i++)
        #pragma unroll
        for (int j=0;j<4;j++)
          acc[i][j] = __builtin_amdgcn_mfma_f32_16x16x32_bf16(aF[i], bF[j], acc[i][j], 0,0,0);
    }
    __syncthreads();
  }

  // epilogue
  #pragma unroll
  for (int i=0;i<4;i++){
    int rowbase = m0 + wm*64 + i*16 + quad*4;     // 4 consecutive rows
    #pragma unroll
    for (int j=0;j<4;j++){
      int col = n0 + wn*64 + j*16 + r16;
      float bsv = bias[col];
      if (mode == 3){
        #pragma unroll
        for (int r=0;r<4;r++)
          dout[(size_t)(rowbase+r)*512 + col] = acc[i][j][r] + bsv;
      } else if (mode == 2){
        int b = rowbase >> 10, s = rowbase & 1023;
        int h = col >> 6, d = col & 63;
        int nh = h*8 + b;
        int sb = s >> 3, ss0 = s & 7;             // rowbase%4==0 -> within one 8-block
        union { ushort_t sh[4]; uint2 u2; } pk;
        #pragma unroll
        for (int r=0;r<4;r++) pk.sh[r] = f2bf(acc[i][j][r] + bsv);
        *(uint2*)&out[ (((size_t)nh*128 + sb)*64 + d)*8 + ss0 ] = pk.u2;
      } else {
        float scl = (mode==0) ? 0.125f : 1.0f;
        int h = col >> 6, d = col & 63;
        #pragma unroll
        for (int r=0;r<4;r++){
          int row = rowbase + r;
          int b = row >> 10, s = row & 1023;
          int nh = h*8 + b;
          out[ ((size_t)nh*1024 + s)*64 + d ] = f2bf((acc[i][j][r] + bsv)*scl);
        }
      }
    }
  }
}

// ---------------------------------------------------------------------------
// Kernel 3: fused attention per (n, 16-query tile).
// Phase 1: S = Q K^T (scores in registers, 16 f32x4/wave)
// Phase 2: per-row top-51 threshold via wave bisection (ballot+popc),
//          p = sel? 1.2*e : e, normalized, written to sP as bf16
// Phase 3: O = P V  (V blocked layout), write merged-head attn buffer (bf16)
// LDS: 32KB union(K/V chunk, 4x1024 f32 row buffer) + 32KB sP = 64KB.
// ---------------------------------------------------------------------------
static __device__ __forceinline__ void stage_chunk(const ushort_t* src, ushort_t* sU,
                                                   int w, int lane){
  #pragma unroll
  for (int i=0;i<8;i++){
    int off = (w*8+i)*512;                 // 1KB piece = 8 rows of 64
    int sub = lane>>3;                     // row within piece (row&7 == sub)
    int gch = (lane&7) ^ sub;              // xor-swizzle to match frag reads
    gll16(src + off + sub*64 + gch*8, sU + off);
  }
}

__global__ __launch_bounds__(256) void attn_k(const ushort_t* ws_q, const ushort_t* ws_k,
     const ushort_t* ws_v, const int* ridx, int nrand, ushort_t* attn){
  __shared__ ushort_t sU[16384];           // 32KB: K/V chunk [256 keys][64] OR sT float[4][1024]
  __shared__ ushort_t sP[16*1024];         // 32KB: normalized probs, bf16, xor-swizzled rows
  float* sT = (float*)sU;

  int tid = threadIdx.x, lane = tid&63, w = tid>>6;
  int r16 = lane&15, quad = lane>>4;
  int n = blockIdx.y, q0 = blockIdx.x*16;
  const ushort_t* Qn = ws_q + (size_t)n*SEQ*DK;
  const ushort_t* Kn = ws_k + (size_t)n*SEQ*DK;
  const ushort_t* Vn = ws_v + (size_t)n*SEQ*DK;

  // rand-column mask, per lane: bit j <-> column j*64+lane
  unsigned rmask = 0;
  for (int i=0;i<nrand;i++){
    int idx = ridx[i];
    if ((idx & 63) == lane) rmask |= 1u << (idx >> 6);
  }

  // Q A-frags (row m = r16, k = t*32 + quad*8 + j)
  bf16x8 aQ[2];
  #pragma unroll
  for (int t=0;t<2;t++)
    aQ[t] = frag16(Qn + (size_t)(q0 + r16)*64 + t*32 + quad*8);

  const f32x4 zero = {0.f,0.f,0.f,0.f};
  f32x4 acc[16];                            // wave's score tiles: cols {c*256 + w*64 + j*16}
  #pragma unroll
  for (int i=0;i<16;i++) acc[i] = zero;

  // ---- Phase 1: scores ----
  #pragma unroll
  for (int c=0;c<4;c++){
    stage_chunk(Kn + c*16384, sU, w, lane);
    __syncthreads();
    #pragma unroll
    for (int j=0;j<4;j++){
      f32x4 a = zero;
      #pragma unroll
      for (int t=0;t<2;t++){
        int row = w*64 + j*16 + r16;       // key index within chunk
        bf16x8 bF = frag16(sU + row*64 + ((t*4 + quad) ^ (row & 7))*8);
        a = __builtin_amdgcn_mfma_f32_16x16x32_bf16(aQ[t], bF, a, 0,0,0);
      }
      acc[c*4+j] = a;
    }
    __syncthreads();
  }

  // ---- Phase 2: per-row top-k + exp + normalize ----
  for (int rg=0; rg<4; rg++){
    __syncthreads();                       // protect previous sT reads / K-chunk reads
    if (quad == rg){                       // quad rg holds global rows rg*4 + reg
      #pragma unroll
      for (int c=0;c<4;c++)
        #pragma unroll
        for (int j=0;j<4;j++){
          int col = c*256 + w*64 + j*16 + r16;
          #pragma unroll
          for (int r=0;r<4;r++) sT[r*1024 + col] = acc[c*4+j][r];
        }
    }
    __syncthreads();
    int grow = rg*4 + w;                   // this wave's row
    float v[16];
    float vmax = -3.0e38f, vmin = 3.0e38f;
    #pragma unroll
    for (int j=0;j<16;j++){
      v[j] = sT[w*1024 + j*64 + lane];
      vmax = fmaxf(vmax, v[j]); vmin = fminf(vmin, v[j]);
    }
    #pragma unroll
    for (int off=32; off>=1; off>>=1){
      vmax = fmaxf(vmax, __shfl_xor(vmax, off));
      vmin = fminf(vmin, __shfl_xor(vmin, off));
    }
    // bisect threshold t: largest with count(v >= t) >= 51
    float lo = vmin, hi = vmax;
    for (int it=0; it<30; it++){
      float mid = 0.5f*(lo+hi);
      int cnt = 0;
      #pragma unroll
      for (int j=0;j<16;j++)
        cnt += __popcll(__ballot(v[j] >= mid));
      if (cnt >= TOPK_N) lo = mid; else hi = mid;
      if (cnt == TOPK_N) break;
    }
    float thr = lo;
    float ps[16]; float lsum = 0.f;
    #pragma unroll
    for (int j=0;j<16;j++){
      bool sel = (v[j] >= thr) || ((rmask >> j) & 1u);
      float p = __expf(v[j] - vmax);
      p = sel ? p*RSCALE : p;
      ps[j] = p; lsum += p;
    }
    #pragma unroll
    for (int off=32; off>=1; off>>=1) lsum += __shfl_xor(lsum, off);
    float rinv = 1.0f / lsum;
    #pragma unroll
    for (int j=0;j<16;j++){
      int col = j*64 + lane;
      int cc = (col>>3) ^ (grow & 7);      // xor-swizzle chunks within the row
      sP[grow*1024 + cc*8 + (col&7)] = f2bf(ps[j]*rinv);
    }
  }
  __syncthreads();

  // ---- Phase 3: O = P V ----
  f32x4 oacc = zero;
  #pragma unroll
  for (int c=0;c<4;c++){
    stage_chunk(Vn + c*16384, sU, w, lane);
    __syncthreads();
    #pragma unroll
    for (int ks=0; ks<8; ks++){
      int g8 = c*32 + ks*4 + quad;         // P chunk index (k = g8*8 + j)
      bf16x8 aF = frag16(sP + r16*1024 + (g8 ^ (r16&7))*8);
      int vg8 = (ks*4 + quad)*64 + (w*16 + r16);   // V group within staged 32KB chunk
      int vrow = vg8 >> 3, vch = vg8 & 7;
      bf16x8 bF = frag16(sU + vrow*64 + (vch ^ (vrow & 7))*8);
      oacc = __builtin_amdgcn_mfma_f32_16x16x32_bf16(aF, bF, oacc, 0,0,0);
    }
    __syncthreads();
  }

  // epilogue: merged-head layout attn[b][s][h*64 + d], bf16
  int h = n >> 3, b = n & 7;
  #pragma unroll
  for (int r=0;r<4;r++){
    int s = q0 + quad*4 + r;
    attn[ ((size_t)(b*1024 + s))*512 + h*64 + w*16 + r16 ] = f2bf(oacc[r]);
  }
}

// ---------------------------------------------------------------------------
extern "C" void kernel_launch(void* const* d_in, const int* in_sizes, int n_in,
                              void* d_out, int out_size, void* d_ws, size_t ws_size,
                              hipStream_t stream){
  const float* Qx  = (const float*)d_in[0];
  const float* KVx = (const float*)d_in[1];
  const float* Wq  = (const float*)d_in[2];
  const float* bq  = (const float*)d_in[3];
  const float* Wk  = (const float*)d_in[4];
  const float* bk  = (const float*)d_in[5];
  const float* Wv  = (const float*)d_in[6];
  const float* bv  = (const float*)d_in[7];
  const float* Wo  = (const float*)d_in[8];
  const float* bo  = (const float*)d_in[9];
  const int* ridx  = (const int*)d_in[10];
  int nrand = in_sizes[10];
  ushort_t* ws = (ushort_t*)d_ws;
  float* dout = (float*)d_out;

  cvt_k<<<dim3(2048,2), 256, 0, stream>>>(Qx, KVx, ws);
  wtrans_k<<<dim3(8,8,4), 256, 0, stream>>>(Wq, Wk, Wv, Wo, ws + OFF_WT);
  gemm_k<<<dim3(4,64,3), 256, 0, stream>>>(ws, bq, bk, bv, bo, dout, 0);
  attn_k<<<dim3(64,64), 256, 0, stream>>>(ws+OFF_Q, ws+OFF_K, ws+OFF_V, ridx, nrand, ws+OFF_A);
  gemm_k<<<dim3(4,64,1), 256, 0, stream>>>(ws, bq, bk, bv, bo, dout, 3);
}

// Round 3
// 335.399 us; speedup vs baseline: 1.1286x; 1.1286x over previous
//
#include <hip/hip_runtime.h>
#include <stdint.h>

typedef unsigned short ushort_t;
typedef __bf16 bf16x8 __attribute__((ext_vector_type(8)));
typedef float f32x4 __attribute__((ext_vector_type(4)));

#define SEQ   1024
#define DK    64
#define TOPK_N 51
#define RSCALE 1.2f

// workspace element offsets (ushort elements). A aliases QX (QX dead after gemm modes 0-2).
#define OFF_WT  0                          // 4 * 512*512
#define OFF_Q   (4*512*512)                // 64*1024*64
#define OFF_K   (OFF_Q  + 64*1024*64)
#define OFF_V   (OFF_K  + 64*1024*64)
#define OFF_QX  (OFF_V  + 64*1024*64)      // 8192*512 bf16 copy of Query_x
#define OFF_KVX (OFF_QX + 8192*512)        // 8192*512 bf16 copy of KeyandValue_x
#define OFF_A   OFF_QX                     // attn output (bf16), reuses QX

static __device__ __forceinline__ ushort_t f2bf(float f){
  union { float f; unsigned u; } x; x.f = f;
  unsigned r = x.u + 0x7FFFu + ((x.u >> 16) & 1u);   // RNE
  return (ushort_t)(r >> 16);
}
static __device__ __forceinline__ ushort_t f2h(float f){
  union { _Float16 h; ushort_t u; } x; x.h = (_Float16)f; return x.u;
}
static __device__ __forceinline__ float h2f(ushort_t u){
  union { ushort_t u; _Float16 h; } x; x.u = u; return (float)x.h;
}
static __device__ __forceinline__ bf16x8 frag16(const ushort_t* p){
  union { uint4 u; bf16x8 b; } x; x.u = *(const uint4*)p; return x.b;
}
// async global->LDS, 16B per lane; lds base wave-uniform (HW adds lane*16)
static __device__ __forceinline__ void gll16(const ushort_t* g, ushort_t* lds){
  __builtin_amdgcn_global_load_lds((const __attribute__((address_space(1))) unsigned*)g,
                                   (__attribute__((address_space(3))) unsigned*)lds,
                                   16, 0, 0);
}

// ---------------------------------------------------------------------------
// Kernel 0: f32 -> bf16 conversion of the two activation tensors
// ---------------------------------------------------------------------------
__global__ __launch_bounds__(256) void cvt_k(const float* qx, const float* kvx, ushort_t* ws){
  const float* src = blockIdx.y ? kvx : qx;
  ushort_t* dst = ws + (blockIdx.y ? OFF_KVX : OFF_QX);
  int i = (blockIdx.x*256 + threadIdx.x) * 8;
  float4 a = *(const float4*)(src + i);
  float4 b = *(const float4*)(src + i + 4);
  union { ushort_t s[8]; uint4 u; } p;
  p.s[0]=f2bf(a.x); p.s[1]=f2bf(a.y); p.s[2]=f2bf(a.z); p.s[3]=f2bf(a.w);
  p.s[4]=f2bf(b.x); p.s[5]=f2bf(b.y); p.s[6]=f2bf(b.z); p.s[7]=f2bf(b.w);
  *(uint4*)(dst + i) = p.u;
}

// ---------------------------------------------------------------------------
// Kernel 1: convert + transpose the four 512x512 f32 weights: WT[n][k] = bf16(W[k][n])
// ---------------------------------------------------------------------------
__global__ __launch_bounds__(256) void wtrans_k(const float* Wq, const float* Wk,
    const float* Wv, const float* Wo, ushort_t* wt){
  __shared__ ushort_t t[64][72];  // +8 pad
  int z = blockIdx.z;
  const float* W = z==0?Wq: z==1?Wk: z==2?Wv: Wo;
  ushort_t* O = wt + (size_t)z*512*512;
  int kt = blockIdx.y*64, nt = blockIdx.x*64;
  int tid = threadIdx.x;
  int r0 = tid>>3, c8 = (tid&7)*8;
  #pragma unroll
  for (int p=0;p<2;p++){
    int r = p*32 + r0;
    float4 a = *(const float4*)&W[(size_t)(kt+r)*512 + nt + c8];
    float4 b = *(const float4*)&W[(size_t)(kt+r)*512 + nt + c8 + 4];
    t[r][c8+0]=f2bf(a.x); t[r][c8+1]=f2bf(a.y); t[r][c8+2]=f2bf(a.z); t[r][c8+3]=f2bf(a.w);
    t[r][c8+4]=f2bf(b.x); t[r][c8+5]=f2bf(b.y); t[r][c8+6]=f2bf(b.z); t[r][c8+7]=f2bf(b.w);
  }
  __syncthreads();
  #pragma unroll
  for (int p=0;p<2;p++){
    int r = p*32 + r0;
    union { ushort_t s[8]; uint4 u; } tmp;
    #pragma unroll
    for (int j=0;j<8;j++) tmp.s[j] = t[c8+j][r];
    *(uint4*)&O[(size_t)(nt+r)*512 + kt + c8] = tmp.u;
  }
}

// ---------------------------------------------------------------------------
// Kernel 2/4: 128x128-tile bf16 GEMM  Y = X*W + b  (W transposed, bf16 in ws).
// mode 0: Q proj (X=QXb)  -> Qs[n][s][64], scaled 1/8 (=1/sqrt(dk))
// mode 1: K proj (X=KVXb) -> Ks[n][s][64]
// mode 2: V proj (X=KVXb) -> Vb[n][sb][d][ss]  (s=sb*8+ss, blocked for PV B-frags)
// mode 3: out proj (X=A)  -> d_out [8192][512] f32
// ---------------------------------------------------------------------------
__global__ __launch_bounds__(256) void gemm_k(ushort_t* ws, const float* bq, const float* bk,
    const float* bv, const float* bo, float* dout, int base_mode){
  int mode = base_mode + blockIdx.z;
  const ushort_t* X  = (mode==0)? ws+OFF_QX : (mode==3)? ws+OFF_A : ws+OFF_KVX;
  const ushort_t* WT = ws + OFF_WT + (size_t)mode*(512*512);
  const float* bias  = (mode==0)?bq:(mode==1)?bk:(mode==2)?bv:bo;
  ushort_t* out = (mode==0)? ws+OFF_Q : (mode==1)? ws+OFF_K : ws+OFF_V;

  __shared__ ushort_t sA[128*64];
  __shared__ ushort_t sB[128*64];
  int tid = threadIdx.x, lane = tid & 63, w = tid >> 6;
  int wm = w & 1, wn = w >> 1;
  int m0 = blockIdx.y * 128, n0 = blockIdx.x * 128;
  int r16 = lane & 15, quad = lane >> 4;
  int srow = lane >> 3, schunk = lane & 7;   // staging: 8 rows x 8 chunks of 16B

  const f32x4 zero = {0.f,0.f,0.f,0.f};
  f32x4 acc[4][4];
  #pragma unroll
  for (int i=0;i<4;i++)
    #pragma unroll
    for (int j=0;j<4;j++) acc[i][j] = zero;

  for (int kb = 0; kb < 8; kb++){
    int k0 = kb*64;
    #pragma unroll
    for (int i=0;i<4;i++){
      int rb = w*32 + i*8;                 // rb % 8 == 0
      int gch = schunk ^ srow;             // xor-swizzle: slot s holds chunk s^(row&7)
      gll16(X  + (size_t)(m0+rb+srow)*512 + k0 + gch*8, sA + rb*64);
      gll16(WT + (size_t)(n0+rb+srow)*512 + k0 + gch*8, sB + rb*64);
    }
    __syncthreads();
    #pragma unroll
    for (int t=0;t<2;t++){
      bf16x8 aF[4], bF[4];
      #pragma unroll
      for (int i=0;i<4;i++){
        int row = wm*64 + i*16 + r16;
        aF[i] = frag16(sA + row*64 + ((t*4 + quad) ^ (row & 7))*8);
      }
      #pragma unroll
      for (int j=0;j<4;j++){
        int row = wn*64 + j*16 + r16;
        bF[j] = frag16(sB + row*64 + ((t*4 + quad) ^ (row & 7))*8);
      }
      #pragma unroll
      for (int i=0;i<4;i++)
        #pragma unroll
        for (int j=0;j<4;j++)
          acc[i][j] = __builtin_amdgcn_mfma_f32_16x16x32_bf16(aF[i], bF[j], acc[i][j], 0,0,0);
    }
    __syncthreads();
  }

  // epilogue
  #pragma unroll
  for (int i=0;i<4;i++){
    int rowbase = m0 + wm*64 + i*16 + quad*4;     // 4 consecutive rows
    #pragma unroll
    for (int j=0;j<4;j++){
      int col = n0 + wn*64 + j*16 + r16;
      float bsv = bias[col];
      if (mode == 3){
        #pragma unroll
        for (int r=0;r<4;r++)
          dout[(size_t)(rowbase+r)*512 + col] = acc[i][j][r] + bsv;
      } else if (mode == 2){
        int b = rowbase >> 10, s = rowbase & 1023;
        int h = col >> 6, d = col & 63;
        int nh = h*8 + b;
        int sb = s >> 3, ss0 = s & 7;             // rowbase%4==0 -> within one 8-block
        union { ushort_t sh[4]; uint2 u2; } pk;
        #pragma unroll
        for (int r=0;r<4;r++) pk.sh[r] = f2bf(acc[i][j][r] + bsv);
        *(uint2*)&out[ (((size_t)nh*128 + sb)*64 + d)*8 + ss0 ] = pk.u2;
      } else {
        float scl = (mode==0) ? 0.125f : 1.0f;
        int h = col >> 6, d = col & 63;
        #pragma unroll
        for (int r=0;r<4;r++){
          int row = rowbase + r;
          int b = row >> 10, s = row & 1023;
          int nh = h*8 + b;
          out[ ((size_t)nh*1024 + s)*64 + d ] = f2bf((acc[i][j][r] + bsv)*scl);
        }
      }
    }
  }
}

// ---------------------------------------------------------------------------
// Kernel 3: fused attention per (n, 16-query tile). Barrier-minimal design:
// Phase 1: S = Q K^T, K B-frags DIRECT from global (no LDS, no barriers)
// Transpose: all 16 rows -> sS (f16, xor-swizzled 16B chunks), 1 barrier
// Phase 2: each wave owns 4 full rows: top-51 threshold via bisection
//          (ballot+popc), exp, normalize; probs overwrite scores in place
//          (bf16 in same slots), no internal barriers; 1 barrier after
// Phase 3: O = P V, V B-frags DIRECT from global (blocked layout), no barriers
// LDS total: 32KB -> 5 blocks/CU.
// ---------------------------------------------------------------------------
__global__ __launch_bounds__(256) void attn_k(const ushort_t* ws_q, const ushort_t* ws_k,
     const ushort_t* ws_v, const int* ridx, int nrand, ushort_t* attn){
  __shared__ ushort_t sS[16*1024];         // 32KB: scores f16 -> probs bf16, in place

  int tid = threadIdx.x, lane = tid&63, w = tid>>6;
  int r16 = lane&15, quad = lane>>4;
  int n = blockIdx.y, q0 = blockIdx.x*16;
  const ushort_t* Qn = ws_q + (size_t)n*SEQ*DK;
  const ushort_t* Kn = ws_k + (size_t)n*SEQ*DK;
  const ushort_t* Vb = ws_v + (size_t)n*SEQ*DK;   // blocked [sb][d][ss]

  // rand-column mask, per lane: bit j <-> column j*64+lane
  unsigned rmask = 0;
  for (int i=0;i<nrand;i++){
    int idx = ridx[i];
    if ((idx & 63) == lane) rmask |= 1u << (idx >> 6);
  }

  // Q A-frags (row m = r16, k = t*32 + quad*8 + j)
  bf16x8 aQ[2];
  #pragma unroll
  for (int t=0;t<2;t++)
    aQ[t] = frag16(Qn + (size_t)(q0 + r16)*64 + t*32 + quad*8);

  const f32x4 zero = {0.f,0.f,0.f,0.f};

  // ---- Phase 1: scores, K direct from global ----
  f32x4 acc[16];                            // wave's tiles: cols c*256 + w*64 + j*16 (+r16)
  #pragma unroll
  for (int c=0;c<4;c++)
    #pragma unroll
    for (int j=0;j<4;j++){
      int row = c*256 + w*64 + j*16 + r16;  // key index
      f32x4 a = zero;
      #pragma unroll
      for (int t=0;t<2;t++){
        bf16x8 bF = frag16(Kn + (size_t)row*64 + t*32 + quad*8);
        a = __builtin_amdgcn_mfma_f32_16x16x32_bf16(aQ[t], bF, a, 0,0,0);
      }
      acc[c*4+j] = a;
    }

  // ---- Transpose all 16 rows into sS as f16 (element (row,col) at
  //      row*1024 + ((col>>3)^(row&7))*8 + (col&7)) ----
  #pragma unroll
  for (int c=0;c<4;c++)
    #pragma unroll
    for (int j=0;j<4;j++){
      int col = c*256 + w*64 + j*16 + r16;
      int c0 = col>>3, c7 = col&7;
      #pragma unroll
      for (int r=0;r<4;r++){
        int row = quad*4 + r;
        sS[row*1024 + ((c0 ^ (row&7))*8) + c7] = f2h(acc[c*4+j][r]);
      }
    }
  __syncthreads();

  // ---- Phase 2: wave w owns rows 4w..4w+3, fully parallel across waves ----
  #pragma unroll 1
  for (int r=0;r<4;r++){
    int row = w*4 + r;
    int rs = row & 7;
    float v[16];
    float vmax = -3.0e38f, vmin = 3.0e38f;
    #pragma unroll
    for (int j=0;j<16;j++){
      int col = j*64 + lane;
      v[j] = h2f(sS[row*1024 + ((col>>3) ^ rs)*8 + (col&7)]);
      vmax = fmaxf(vmax, v[j]); vmin = fminf(vmin, v[j]);
    }
    #pragma unroll
    for (int off=32; off>=1; off>>=1){
      vmax = fmaxf(vmax, __shfl_xor(vmax, off));
      vmin = fminf(vmin, __shfl_xor(vmin, off));
    }
    // bisect threshold: largest t with count(v >= t) >= 51
    float lo = vmin, hi = vmax;
    for (int it=0; it<20; it++){
      float mid = 0.5f*(lo+hi);
      int cnt = 0;
      #pragma unroll
      for (int j=0;j<16;j++)
        cnt += __popcll(__ballot(v[j] >= mid));
      if (cnt >= TOPK_N) lo = mid; else hi = mid;
      if (cnt == TOPK_N) break;
    }
    float thr = lo;
    float ps[16]; float lsum = 0.f;
    #pragma unroll
    for (int j=0;j<16;j++){
      bool sel = (v[j] >= thr) || ((rmask >> j) & 1u);
      float p = __expf(v[j] - vmax);
      p = sel ? p*RSCALE : p;
      ps[j] = p; lsum += p;
    }
    #pragma unroll
    for (int off=32; off>=1; off>>=1) lsum += __shfl_xor(lsum, off);
    float rinv = 1.0f / lsum;
    #pragma unroll
    for (int j=0;j<16;j++){
      int col = j*64 + lane;
      sS[row*1024 + ((col>>3) ^ rs)*8 + (col&7)] = f2bf(ps[j]*rinv);
    }
  }
  __syncthreads();

  // ---- Phase 3: O = P V, V direct from global (blocked layout) ----
  f32x4 oa0 = zero, oa1 = zero;
  #pragma unroll
  for (int kk=0; kk<32; kk++){
    int g8 = kk*4 + quad;                   // 8-element k-chunk index
    bf16x8 aF = frag16(sS + r16*1024 + (g8 ^ (r16&7))*8);
    bf16x8 bF = frag16(Vb + ((size_t)g8*64 + w*16 + r16)*8);
    if (kk & 1) oa1 = __builtin_amdgcn_mfma_f32_16x16x32_bf16(aF, bF, oa1, 0,0,0);
    else        oa0 = __builtin_amdgcn_mfma_f32_16x16x32_bf16(aF, bF, oa0, 0,0,0);
  }
  f32x4 oacc = oa0 + oa1;

  // epilogue: merged-head layout attn[b][s][h*64 + d], bf16
  int h = n >> 3, b = n & 7;
  #pragma unroll
  for (int r=0;r<4;r++){
    int s = q0 + quad*4 + r;
    attn[ ((size_t)(b*1024 + s))*512 + h*64 + w*16 + r16 ] = f2bf(oacc[r]);
  }
}

// ---------------------------------------------------------------------------
extern "C" void kernel_launch(void* const* d_in, const int* in_sizes, int n_in,
                              void* d_out, int out_size, void* d_ws, size_t ws_size,
                              hipStream_t stream){
  const float* Qx  = (const float*)d_in[0];
  const float* KVx = (const float*)d_in[1];
  const float* Wq  = (const float*)d_in[2];
  const float* bq  = (const float*)d_in[3];
  const float* Wk  = (const float*)d_in[4];
  const float* bk  = (const float*)d_in[5];
  const float* Wv  = (const float*)d_in[6];
  const float* bv  = (const float*)d_in[7];
  const float* Wo  = (const float*)d_in[8];
  const float* bo  = (const float*)d_in[9];
  const int* ridx  = (const int*)d_in[10];
  int nrand = in_sizes[10];
  ushort_t* ws = (ushort_t*)d_ws;
  float* dout = (float*)d_out;

  cvt_k<<<dim3(2048,2), 256, 0, stream>>>(Qx, KVx, ws);
  wtrans_k<<<dim3(8,8,4), 256, 0, stream>>>(Wq, Wk, Wv, Wo, ws + OFF_WT);
  gemm_k<<<dim3(4,64,3), 256, 0, stream>>>(ws, bq, bk, bv, bo, dout, 0);
  attn_k<<<dim3(64,64), 256, 0, stream>>>(ws+OFF_Q, ws+OFF_K, ws+OFF_V, ridx, nrand, ws+OFF_A);
  gemm_k<<<dim3(4,64,1), 256, 0, stream>>>(ws, bq, bk, bv, bo, dout, 3);
}

// Round 4
// 321.048 us; speedup vs baseline: 1.1790x; 1.0447x over previous
//
#include <hip/hip_runtime.h>
#include <stdint.h>

typedef unsigned short ushort_t;
typedef __bf16 bf16x8 __attribute__((ext_vector_type(8)));
typedef float f32x4 __attribute__((ext_vector_type(4)));

#define SEQ   1024
#define DK    64
#define TOPK_N 51
#define RSCALE 1.2f

// workspace element offsets (ushort elements). A aliases QX (QX dead after gemm modes 0-2).
#define OFF_WT  0                          // 4 * 512*512
#define OFF_Q   (4*512*512)                // 64*1024*64
#define OFF_K   (OFF_Q  + 64*1024*64)
#define OFF_V   (OFF_K  + 64*1024*64)
#define OFF_QX  (OFF_V  + 64*1024*64)      // 8192*512 bf16 copy of Query_x
#define OFF_KVX (OFF_QX + 8192*512)        // 8192*512 bf16 copy of KeyandValue_x
#define OFF_MASK (OFF_KVX + 8192*512)      // 64 u16: rand-column bitmap per lane
#define OFF_A   OFF_QX                     // attn output (bf16), reuses QX

static __device__ __forceinline__ ushort_t f2bf(float f){
  union { float f; unsigned u; } x; x.f = f;
  unsigned r = x.u + 0x7FFFu + ((x.u >> 16) & 1u);   // RNE
  return (ushort_t)(r >> 16);
}
static __device__ __forceinline__ ushort_t f2h(float f){
  union { _Float16 h; ushort_t u; } x; x.h = (_Float16)f; return x.u;
}
static __device__ __forceinline__ float h2f(ushort_t u){
  union { ushort_t u; _Float16 h; } x; x.u = u; return (float)x.h;
}
static __device__ __forceinline__ bf16x8 frag16(const ushort_t* p){
  union { uint4 u; bf16x8 b; } x; x.u = *(const uint4*)p; return x.b;
}
// async global->LDS, 16B per lane; lds base wave-uniform (HW adds lane*16)
static __device__ __forceinline__ void gll16(const ushort_t* g, ushort_t* lds){
  __builtin_amdgcn_global_load_lds((const __attribute__((address_space(1))) unsigned*)g,
                                   (__attribute__((address_space(3))) unsigned*)lds,
                                   16, 0, 0);
}

// ---------------------------------------------------------------------------
// Kernel 0a: rand-column bitmap: bitmap[lane] bit j <=> column j*64+lane chosen
// ---------------------------------------------------------------------------
__global__ __launch_bounds__(128) void mask_k(const int* ridx, int nrand, ushort_t* bitmap){
  __shared__ unsigned wds[64];
  int t = threadIdx.x;
  if (t < 64) wds[t] = 0;
  __syncthreads();
  for (int i = t; i < nrand; i += 128){
    int idx = ridx[i];
    atomicOr(&wds[idx & 63], 1u << (idx >> 6));
  }
  __syncthreads();
  if (t < 64) bitmap[t] = (ushort_t)wds[t];
}

// ---------------------------------------------------------------------------
// Kernel 0: f32 -> bf16 conversion of the two activation tensors
// ---------------------------------------------------------------------------
__global__ __launch_bounds__(256) void cvt_k(const float* qx, const float* kvx, ushort_t* ws){
  const float* src = blockIdx.y ? kvx : qx;
  ushort_t* dst = ws + (blockIdx.y ? OFF_KVX : OFF_QX);
  int i = (blockIdx.x*256 + threadIdx.x) * 8;
  float4 a = *(const float4*)(src + i);
  float4 b = *(const float4*)(src + i + 4);
  union { ushort_t s[8]; uint4 u; } p;
  p.s[0]=f2bf(a.x); p.s[1]=f2bf(a.y); p.s[2]=f2bf(a.z); p.s[3]=f2bf(a.w);
  p.s[4]=f2bf(b.x); p.s[5]=f2bf(b.y); p.s[6]=f2bf(b.z); p.s[7]=f2bf(b.w);
  *(uint4*)(dst + i) = p.u;
}

// ---------------------------------------------------------------------------
// Kernel 1: convert + transpose the four 512x512 f32 weights: WT[n][k] = bf16(W[k][n])
// ---------------------------------------------------------------------------
__global__ __launch_bounds__(256) void wtrans_k(const float* Wq, const float* Wk,
    const float* Wv, const float* Wo, ushort_t* wt){
  __shared__ ushort_t t[64][72];  // +8 pad
  int z = blockIdx.z;
  const float* W = z==0?Wq: z==1?Wk: z==2?Wv: Wo;
  ushort_t* O = wt + (size_t)z*512*512;
  int kt = blockIdx.y*64, nt = blockIdx.x*64;
  int tid = threadIdx.x;
  int r0 = tid>>3, c8 = (tid&7)*8;
  #pragma unroll
  for (int p=0;p<2;p++){
    int r = p*32 + r0;
    float4 a = *(const float4*)&W[(size_t)(kt+r)*512 + nt + c8];
    float4 b = *(const float4*)&W[(size_t)(kt+r)*512 + nt + c8 + 4];
    t[r][c8+0]=f2bf(a.x); t[r][c8+1]=f2bf(a.y); t[r][c8+2]=f2bf(a.z); t[r][c8+3]=f2bf(a.w);
    t[r][c8+4]=f2bf(b.x); t[r][c8+5]=f2bf(b.y); t[r][c8+6]=f2bf(b.z); t[r][c8+7]=f2bf(b.w);
  }
  __syncthreads();
  #pragma unroll
  for (int p=0;p<2;p++){
    int r = p*32 + r0;
    union { ushort_t s[8]; uint4 u; } tmp;
    #pragma unroll
    for (int j=0;j<8;j++) tmp.s[j] = t[c8+j][r];
    *(uint4*)&O[(size_t)(nt+r)*512 + kt + c8] = tmp.u;
  }
}

// ---------------------------------------------------------------------------
// Kernel 2/4: 128x128-tile bf16 GEMM  Y = X*W + b  (W transposed, bf16 in ws).
// mode 0: Q proj (X=QXb)  -> Qs[n][s][64], scaled 1/8 (=1/sqrt(dk))
// mode 1: K proj (X=KVXb) -> Ks[n][s][64]
// mode 2: V proj (X=KVXb) -> Vb[n][sb][d][ss]  (s=sb*8+ss, blocked for PV B-frags)
// mode 3: out proj (X=A)  -> d_out [8192][512] f32
// ---------------------------------------------------------------------------
__global__ __launch_bounds__(256) void gemm_k(ushort_t* ws, const float* bq, const float* bk,
    const float* bv, const float* bo, float* dout, int base_mode){
  int mode = base_mode + blockIdx.z;
  const ushort_t* X  = (mode==0)? ws+OFF_QX : (mode==3)? ws+OFF_A : ws+OFF_KVX;
  const ushort_t* WT = ws + OFF_WT + (size_t)mode*(512*512);
  const float* bias  = (mode==0)?bq:(mode==1)?bk:(mode==2)?bv:bo;
  ushort_t* out = (mode==0)? ws+OFF_Q : (mode==1)? ws+OFF_K : ws+OFF_V;

  __shared__ ushort_t sA[128*64];
  __shared__ ushort_t sB[128*64];
  int tid = threadIdx.x, lane = tid & 63, w = tid >> 6;
  int wm = w & 1, wn = w >> 1;
  int m0 = blockIdx.y * 128, n0 = blockIdx.x * 128;
  int r16 = lane & 15, quad = lane >> 4;
  int srow = lane >> 3, schunk = lane & 7;   // staging: 8 rows x 8 chunks of 16B

  const f32x4 zero = {0.f,0.f,0.f,0.f};
  f32x4 acc[4][4];
  #pragma unroll
  for (int i=0;i<4;i++)
    #pragma unroll
    for (int j=0;j<4;j++) acc[i][j] = zero;

  for (int kb = 0; kb < 8; kb++){
    int k0 = kb*64;
    #pragma unroll
    for (int i=0;i<4;i++){
      int rb = w*32 + i*8;                 // rb % 8 == 0
      int gch = schunk ^ srow;             // xor-swizzle: slot s holds chunk s^(row&7)
      gll16(X  + (size_t)(m0+rb+srow)*512 + k0 + gch*8, sA + rb*64);
      gll16(WT + (size_t)(n0+rb+srow)*512 + k0 + gch*8, sB + rb*64);
    }
    __syncthreads();
    #pragma unroll
    for (int t=0;t<2;t++){
      bf16x8 aF[4], bF[4];
      #pragma unroll
      for (int i=0;i<4;i++){
        int row = wm*64 + i*16 + r16;
        aF[i] = frag16(sA + row*64 + ((t*4 + quad) ^ (row & 7))*8);
      }
      #pragma unroll
      for (int j=0;j<4;j++){
        int row = wn*64 + j*16 + r16;
        bF[j] = frag16(sB + row*64 + ((t*4 + quad) ^ (row & 7))*8);
      }
      #pragma unroll
      for (int i=0;i<4;i++)
        #pragma unroll
        for (int j=0;j<4;j++)
          acc[i][j] = __builtin_amdgcn_mfma_f32_16x16x32_bf16(aF[i], bF[j], acc[i][j], 0,0,0);
    }
    __syncthreads();
  }

  // epilogue
  #pragma unroll
  for (int i=0;i<4;i++){
    int rowbase = m0 + wm*64 + i*16 + quad*4;     // 4 consecutive rows
    #pragma unroll
    for (int j=0;j<4;j++){
      int col = n0 + wn*64 + j*16 + r16;
      float bsv = bias[col];
      if (mode == 3){
        #pragma unroll
        for (int r=0;r<4;r++)
          dout[(size_t)(rowbase+r)*512 + col] = acc[i][j][r] + bsv;
      } else if (mode == 2){
        int b = rowbase >> 10, s = rowbase & 1023;
        int h = col >> 6, d = col & 63;
        int nh = h*8 + b;
        int sb = s >> 3, ss0 = s & 7;             // rowbase%4==0 -> within one 8-block
        union { ushort_t sh[4]; uint2 u2; } pk;
        #pragma unroll
        for (int r=0;r<4;r++) pk.sh[r] = f2bf(acc[i][j][r] + bsv);
        *(uint2*)&out[ (((size_t)nh*128 + sb)*64 + d)*8 + ss0 ] = pk.u2;
      } else {
        float scl = (mode==0) ? 0.125f : 1.0f;
        int h = col >> 6, d = col & 63;
        #pragma unroll
        for (int r=0;r<4;r++){
          int row = rowbase + r;
          int b = row >> 10, s = row & 1023;
          int nh = h*8 + b;
          out[ ((size_t)nh*1024 + s)*64 + d ] = f2bf((acc[i][j][r] + bsv)*scl);
        }
      }
    }
  }
}

// ---------------------------------------------------------------------------
// Kernel 3: fused attention per (n, 16-query tile). Latency-focused design:
// - XCD-swizzled flat grid: each XCD owns 8 heads -> K/V (2MB) L2-resident
// - rand mask: ONE u16 load (precomputed by mask_k)
// - Phase 1: S = Q K^T, K direct from global; 2 halves of 8 tiles so only
//   32 acc VGPRs live -> deep load pipelining; transpose-write f16 to sS
// - Phase 2: 4 rows per wave processed INTERLEAVED: shfl-reduction chains and
//   bisection iterations of the 4 independent rows overlap
// - Phase 3: O = P V, V direct from global (blocked layout)
// LDS 32KB, 2 barriers total.
// ---------------------------------------------------------------------------
__global__ __launch_bounds__(256) void attn_k(const ushort_t* ws_q, const ushort_t* ws_k,
     const ushort_t* ws_v, const ushort_t* maskp, ushort_t* attn){
  __shared__ ushort_t sS[16*1024];         // 32KB: scores f16 -> probs bf16, in place

  int tid = threadIdx.x, lane = tid&63, w = tid>>6;
  int r16 = lane&15, quad = lane>>4;
  // XCD swizzle: each XCD gets a contiguous span of 8 heads
  int gid = blockIdx.x;
  int n  = (gid & 7)*8 + ((gid >> 3) >> 6);
  int q0 = ((gid >> 3) & 63) * 16;
  const ushort_t* Qn = ws_q + (size_t)n*SEQ*DK;
  const ushort_t* Kn = ws_k + (size_t)n*SEQ*DK;
  const ushort_t* Vb = ws_v + (size_t)n*SEQ*DK;   // blocked [sb][d][ss]

  unsigned rmask = (unsigned)maskp[lane];  // bit j <-> column j*64+lane

  // Q A-frags (row m = r16, k = t*32 + quad*8 + j)
  bf16x8 aQ[2];
  #pragma unroll
  for (int t=0;t<2;t++)
    aQ[t] = frag16(Qn + (size_t)(q0 + r16)*64 + t*32 + quad*8);

  const f32x4 zero = {0.f,0.f,0.f,0.f};

  // ---- Phase 1: scores, K direct from global; 2 halves of 8 tiles ----
  #pragma unroll
  for (int half=0; half<2; half++){
    f32x4 acc[8];
    #pragma unroll
    for (int cj=0; cj<8; cj++){
      int c = half*2 + (cj>>2), j = cj&3;
      int row = c*256 + w*64 + j*16 + r16;  // key index
      f32x4 a = zero;
      #pragma unroll
      for (int t=0;t<2;t++){
        bf16x8 bF = frag16(Kn + (size_t)row*64 + t*32 + quad*8);
        a = __builtin_amdgcn_mfma_f32_16x16x32_bf16(aQ[t], bF, a, 0,0,0);
      }
      acc[cj] = a;
    }
    // transpose-write these 8 tiles as f16 (element (row,col) at
    // row*1024 + ((col>>3)^(row&7))*8 + (col&7))
    #pragma unroll
    for (int cj=0; cj<8; cj++){
      int c = half*2 + (cj>>2), j = cj&3;
      int col = c*256 + w*64 + j*16 + r16;
      int c0 = col>>3, c7 = col&7;
      #pragma unroll
      for (int r=0;r<4;r++){
        int row = quad*4 + r;
        sS[row*1024 + ((c0 ^ (row&7))*8) + c7] = f2h(acc[cj][r]);
      }
    }
  }
  __syncthreads();

  // ---- Phase 2: wave w owns rows 4w..4w+3, all 4 rows interleaved ----
  float v[4][16];
  float vmax[4], vmin[4];
  #pragma unroll
  for (int r=0;r<4;r++){ vmax[r] = -3.0e38f; vmin[r] = 3.0e38f; }
  #pragma unroll
  for (int r=0;r<4;r++){
    int row = w*4 + r, rs = row & 7;
    #pragma unroll
    for (int j=0;j<16;j++){
      int col = j*64 + lane;
      v[r][j] = h2f(sS[row*1024 + ((col>>3) ^ rs)*8 + (col&7)]);
      vmax[r] = fmaxf(vmax[r], v[r][j]); vmin[r] = fminf(vmin[r], v[r][j]);
    }
  }
  #pragma unroll
  for (int off=32; off>=1; off>>=1){
    #pragma unroll
    for (int r=0;r<4;r++){
      vmax[r] = fmaxf(vmax[r], __shfl_xor(vmax[r], off));
      vmin[r] = fminf(vmin[r], __shfl_xor(vmin[r], off));
    }
  }
  // 4 interleaved bisections: largest thr with count(v >= thr) >= 51
  float lo[4], hi[4];
  #pragma unroll
  for (int r=0;r<4;r++){ lo[r] = vmin[r]; hi[r] = vmax[r]; }
  int done = 0;
  for (int it=0; it<24 && done != 15; it++){
    #pragma unroll
    for (int r=0;r<4;r++){
      if (!((done >> r) & 1)){
        float mid = 0.5f*(lo[r]+hi[r]);
        int cnt = 0;
        #pragma unroll
        for (int j=0;j<16;j++)
          cnt += __popcll(__ballot(v[r][j] >= mid));
        if (cnt >= TOPK_N) lo[r] = mid; else hi[r] = mid;
        if (cnt == TOPK_N) done |= 1 << r;
      }
    }
  }
  // exp + scale + normalize (probs overwrite v)
  float ls[4];
  #pragma unroll
  for (int r=0;r<4;r++){
    float thr = lo[r], s = 0.f;
    #pragma unroll
    for (int j=0;j<16;j++){
      bool sel = (v[r][j] >= thr) || ((rmask >> j) & 1u);
      float p = __expf(v[r][j] - vmax[r]);
      p = sel ? p*RSCALE : p;
      v[r][j] = p; s += p;
    }
    ls[r] = s;
  }
  #pragma unroll
  for (int off=32; off>=1; off>>=1){
    #pragma unroll
    for (int r=0;r<4;r++) ls[r] += __shfl_xor(ls[r], off);
  }
  #pragma unroll
  for (int r=0;r<4;r++){
    int row = w*4 + r, rs = row & 7;
    float rinv = 1.0f / ls[r];
    #pragma unroll
    for (int j=0;j<16;j++){
      int col = j*64 + lane;
      sS[row*1024 + ((col>>3) ^ rs)*8 + (col&7)] = f2bf(v[r][j]*rinv);
    }
  }
  __syncthreads();

  // ---- Phase 3: O = P V, V direct from global (blocked layout) ----
  f32x4 oa0 = zero, oa1 = zero;
  #pragma unroll
  for (int kk=0; kk<32; kk++){
    int g8 = kk*4 + quad;                   // 8-element k-chunk index
    bf16x8 aF = frag16(sS + r16*1024 + (g8 ^ (r16&7))*8);
    bf16x8 bF = frag16(Vb + ((size_t)g8*64 + w*16 + r16)*8);
    if (kk & 1) oa1 = __builtin_amdgcn_mfma_f32_16x16x32_bf16(aF, bF, oa1, 0,0,0);
    else        oa0 = __builtin_amdgcn_mfma_f32_16x16x32_bf16(aF, bF, oa0, 0,0,0);
  }
  f32x4 oacc = oa0 + oa1;

  // epilogue: merged-head layout attn[b][s][h*64 + d], bf16
  int h = n >> 3, b = n & 7;
  #pragma unroll
  for (int r=0;r<4;r++){
    int s = q0 + quad*4 + r;
    attn[ ((size_t)(b*1024 + s))*512 + h*64 + w*16 + r16 ] = f2bf(oacc[r]);
  }
}

// ---------------------------------------------------------------------------
extern "C" void kernel_launch(void* const* d_in, const int* in_sizes, int n_in,
                              void* d_out, int out_size, void* d_ws, size_t ws_size,
                              hipStream_t stream){
  const float* Qx  = (const float*)d_in[0];
  const float* KVx = (const float*)d_in[1];
  const float* Wq  = (const float*)d_in[2];
  const float* bq  = (const float*)d_in[3];
  const float* Wk  = (const float*)d_in[4];
  const float* bk  = (const float*)d_in[5];
  const float* Wv  = (const float*)d_in[6];
  const float* bv  = (const float*)d_in[7];
  const float* Wo  = (const float*)d_in[8];
  const float* bo  = (const float*)d_in[9];
  const int* ridx  = (const int*)d_in[10];
  int nrand = in_sizes[10];
  ushort_t* ws = (ushort_t*)d_ws;
  float* dout = (float*)d_out;

  mask_k<<<1, 128, 0, stream>>>(ridx, nrand, ws + OFF_MASK);
  cvt_k<<<dim3(2048,2), 256, 0, stream>>>(Qx, KVx, ws);
  wtrans_k<<<dim3(8,8,4), 256, 0, stream>>>(Wq, Wk, Wv, Wo, ws + OFF_WT);
  gemm_k<<<dim3(4,64,3), 256, 0, stream>>>(ws, bq, bk, bv, bo, dout, 0);
  attn_k<<<4096, 256, 0, stream>>>(ws+OFF_Q, ws+OFF_K, ws+OFF_V, ws+OFF_MASK, ws+OFF_A);
  gemm_k<<<dim3(4,64,1), 256, 0, stream>>>(ws, bq, bk, bv, bo, dout, 3);
}

// Round 5
// 264.028 us; speedup vs baseline: 1.4336x; 1.2160x over previous
//
#include <hip/hip_runtime.h>
#include <stdint.h>

typedef unsigned short ushort_t;
typedef __bf16 bf16x8 __attribute__((ext_vector_type(8)));
typedef _Float16 f16x8v __attribute__((ext_vector_type(8)));
typedef float f32x4 __attribute__((ext_vector_type(4)));

#define SEQ   1024
#define DK    64
#define TOPK_N 51
#define RSCALE 1.2f

// workspace element offsets (ushort elements). A aliases QX (QX dead after gemm modes 0-2).
#define OFF_WT  0                          // 4 * 512*512
#define OFF_Q   (4*512*512)                // 64*1024*64
#define OFF_K   (OFF_Q  + 64*1024*64)      // K, d-blocked: [nh][d>>3][key][d&7]
#define OFF_V   (OFF_K  + 64*1024*64)      // V (f16), k-blocked: [nh][sb][d][ss]
#define OFF_QX  (OFF_V  + 64*1024*64)      // 8192*512 bf16 copy of Query_x
#define OFF_KVX (OFF_QX + 8192*512)        // 8192*512 bf16 copy of KeyandValue_x
#define OFF_MASK (OFF_KVX + 8192*512)      // 64 u16: rand-column bitmap (pair layout)
#define OFF_A   OFF_QX                     // attn output (bf16), reuses QX

static __device__ __forceinline__ ushort_t f2bf(float f){
  union { float f; unsigned u; } x; x.f = f;
  unsigned r = x.u + 0x7FFFu + ((x.u >> 16) & 1u);   // RNE
  return (ushort_t)(r >> 16);
}
static __device__ __forceinline__ ushort_t f2h(float f){
  union { _Float16 h; ushort_t u; } x; x.h = (_Float16)f; return x.u;
}
static __device__ __forceinline__ float h2f(ushort_t u){
  union { ushort_t u; _Float16 h; } x; x.u = u; return (float)x.h;
}
static __device__ __forceinline__ bf16x8 frag16(const ushort_t* p){
  union { uint4 u; bf16x8 b; } x; x.u = *(const uint4*)p; return x.b;
}
static __device__ __forceinline__ f16x8v frag16h(const ushort_t* p){
  union { uint4 u; f16x8v h; } x; x.u = *(const uint4*)p; return x.h;
}
// async global->LDS, 16B per lane; lds base wave-uniform (HW adds lane*16)
static __device__ __forceinline__ void gll16(const ushort_t* g, ushort_t* lds){
  __builtin_amdgcn_global_load_lds((const __attribute__((address_space(1))) unsigned*)g,
                                   (__attribute__((address_space(3))) unsigned*)lds,
                                   16, 0, 0);
}

// ---------------------------------------------------------------------------
// Kernel 0a: rand-column bitmap, PAIR layout:
// bitmap[r] (r=0..63) bit (2j+e) <=> column j*128 + r*2 + e chosen
// ---------------------------------------------------------------------------
__global__ __launch_bounds__(128) void mask_k(const int* ridx, int nrand, ushort_t* bitmap){
  __shared__ unsigned wds[64];
  int t = threadIdx.x;
  if (t < 64) wds[t] = 0;
  __syncthreads();
  for (int i = t; i < nrand; i += 128){
    int col = ridx[i];
    atomicOr(&wds[(col & 127) >> 1], 1u << (2*(col >> 7) + (col & 1)));
  }
  __syncthreads();
  if (t < 64) bitmap[t] = (ushort_t)wds[t];
}

// ---------------------------------------------------------------------------
// Kernel 0: f32 -> bf16 conversion of the two activation tensors
// ---------------------------------------------------------------------------
__global__ __launch_bounds__(256) void cvt_k(const float* qx, const float* kvx, ushort_t* ws){
  const float* src = blockIdx.y ? kvx : qx;
  ushort_t* dst = ws + (blockIdx.y ? OFF_KVX : OFF_QX);
  int i = (blockIdx.x*256 + threadIdx.x) * 8;
  float4 a = *(const float4*)(src + i);
  float4 b = *(const float4*)(src + i + 4);
  union { ushort_t s[8]; uint4 u; } p;
  p.s[0]=f2bf(a.x); p.s[1]=f2bf(a.y); p.s[2]=f2bf(a.z); p.s[3]=f2bf(a.w);
  p.s[4]=f2bf(b.x); p.s[5]=f2bf(b.y); p.s[6]=f2bf(b.z); p.s[7]=f2bf(b.w);
  *(uint4*)(dst + i) = p.u;
}

// ---------------------------------------------------------------------------
// Kernel 1: convert + transpose the four 512x512 f32 weights: WT[n][k] = bf16(W[k][n])
// ---------------------------------------------------------------------------
__global__ __launch_bounds__(256) void wtrans_k(const float* Wq, const float* Wk,
    const float* Wv, const float* Wo, ushort_t* wt){
  __shared__ ushort_t t[64][72];  // +8 pad
  int z = blockIdx.z;
  const float* W = z==0?Wq: z==1?Wk: z==2?Wv: Wo;
  ushort_t* O = wt + (size_t)z*512*512;
  int kt = blockIdx.y*64, nt = blockIdx.x*64;
  int tid = threadIdx.x;
  int r0 = tid>>3, c8 = (tid&7)*8;
  #pragma unroll
  for (int p=0;p<2;p++){
    int r = p*32 + r0;
    float4 a = *(const float4*)&W[(size_t)(kt+r)*512 + nt + c8];
    float4 b = *(const float4*)&W[(size_t)(kt+r)*512 + nt + c8 + 4];
    t[r][c8+0]=f2bf(a.x); t[r][c8+1]=f2bf(a.y); t[r][c8+2]=f2bf(a.z); t[r][c8+3]=f2bf(a.w);
    t[r][c8+4]=f2bf(b.x); t[r][c8+5]=f2bf(b.y); t[r][c8+6]=f2bf(b.z); t[r][c8+7]=f2bf(b.w);
  }
  __syncthreads();
  #pragma unroll
  for (int p=0;p<2;p++){
    int r = p*32 + r0;
    union { ushort_t s[8]; uint4 u; } tmp;
    #pragma unroll
    for (int j=0;j<8;j++) tmp.s[j] = t[c8+j][r];
    *(uint4*)&O[(size_t)(nt+r)*512 + kt + c8] = tmp.u;
  }
}

// ---------------------------------------------------------------------------
// Kernel 2/4: 128x128-tile bf16 GEMM  Y = X*W + b  (W transposed, bf16 in ws).
// mode 0: Q proj (X=QXb)  -> Qs[n][s][64], scaled 1/8 (=1/sqrt(dk))
// mode 1: K proj (X=KVXb) -> Kd[n][d>>3][key][d&7]  (d-blocked for QK^T B-frags)
// mode 2: V proj (X=KVXb) -> Vb[n][sb][d][ss] in F16 (k-blocked for PV B-frags)
// mode 3: out proj (X=A)  -> d_out [8192][512] f32
// ---------------------------------------------------------------------------
__global__ __launch_bounds__(256) void gemm_k(ushort_t* ws, const float* bq, const float* bk,
    const float* bv, const float* bo, float* dout, int base_mode){
  int mode = base_mode + blockIdx.z;
  const ushort_t* X  = (mode==0)? ws+OFF_QX : (mode==3)? ws+OFF_A : ws+OFF_KVX;
  const ushort_t* WT = ws + OFF_WT + (size_t)mode*(512*512);
  const float* bias  = (mode==0)?bq:(mode==1)?bk:(mode==2)?bv:bo;
  ushort_t* out = (mode==0)? ws+OFF_Q : (mode==1)? ws+OFF_K : ws+OFF_V;

  __shared__ ushort_t sA[128*64];
  __shared__ ushort_t sB[128*64];
  int tid = threadIdx.x, lane = tid & 63, w = tid >> 6;
  int wm = w & 1, wn = w >> 1;
  int m0 = blockIdx.y * 128, n0 = blockIdx.x * 128;
  int r16 = lane & 15, quad = lane >> 4;
  int srow = lane >> 3, schunk = lane & 7;   // staging: 8 rows x 8 chunks of 16B

  const f32x4 zero = {0.f,0.f,0.f,0.f};
  f32x4 acc[4][4];
  #pragma unroll
  for (int i=0;i<4;i++)
    #pragma unroll
    for (int j=0;j<4;j++) acc[i][j] = zero;

  for (int kb = 0; kb < 8; kb++){
    int k0 = kb*64;
    #pragma unroll
    for (int i=0;i<4;i++){
      int rb = w*32 + i*8;                 // rb % 8 == 0
      int gch = schunk ^ srow;             // xor-swizzle: slot s holds chunk s^(row&7)
      gll16(X  + (size_t)(m0+rb+srow)*512 + k0 + gch*8, sA + rb*64);
      gll16(WT + (size_t)(n0+rb+srow)*512 + k0 + gch*8, sB + rb*64);
    }
    __syncthreads();
    #pragma unroll
    for (int t=0;t<2;t++){
      bf16x8 aF[4], bF[4];
      #pragma unroll
      for (int i=0;i<4;i++){
        int row = wm*64 + i*16 + r16;
        aF[i] = frag16(sA + row*64 + ((t*4 + quad) ^ (row & 7))*8);
      }
      #pragma unroll
      for (int j=0;j<4;j++){
        int row = wn*64 + j*16 + r16;
        bF[j] = frag16(sB + row*64 + ((t*4 + quad) ^ (row & 7))*8);
      }
      #pragma unroll
      for (int i=0;i<4;i++)
        #pragma unroll
        for (int j=0;j<4;j++)
          acc[i][j] = __builtin_amdgcn_mfma_f32_16x16x32_bf16(aF[i], bF[j], acc[i][j], 0,0,0);
    }
    __syncthreads();
  }

  // epilogue
  #pragma unroll
  for (int i=0;i<4;i++){
    int rowbase = m0 + wm*64 + i*16 + quad*4;     // 4 consecutive rows
    #pragma unroll
    for (int j=0;j<4;j++){
      int col = n0 + wn*64 + j*16 + r16;
      float bsv = bias[col];
      if (mode == 3){
        #pragma unroll
        for (int r=0;r<4;r++)
          dout[(size_t)(rowbase+r)*512 + col] = acc[i][j][r] + bsv;
      } else if (mode == 2){
        int b = rowbase >> 10, s = rowbase & 1023;
        int h = col >> 6, d = col & 63;
        int nh = h*8 + b;
        int sb = s >> 3, ss0 = s & 7;             // rowbase%4==0 -> within one 8-block
        union { ushort_t sh[4]; uint2 u2; } pk;   // F16 V
        #pragma unroll
        for (int r=0;r<4;r++) pk.sh[r] = f2h(acc[i][j][r] + bsv);
        *(uint2*)&out[ (((size_t)nh*128 + sb)*64 + d)*8 + ss0 ] = pk.u2;
      } else if (mode == 1){
        int b = rowbase >> 10;
        int h = col >> 6, d = col & 63;
        int nh = h*8 + b;
        // Kd[nh][d>>3][key][d&7]
        size_t base = (size_t)nh*65536 + (size_t)(d>>3)*8192 + (d&7);
        #pragma unroll
        for (int r=0;r<4;r++){
          int s = (rowbase + r) & 1023;
          out[ base + (size_t)s*8 ] = f2bf(acc[i][j][r] + bsv);
        }
      } else {
        int h = col >> 6, d = col & 63;
        #pragma unroll
        for (int r=0;r<4;r++){
          int row = rowbase + r;
          int b = row >> 10, s = row & 1023;
          int nh = h*8 + b;
          out[ ((size_t)nh*1024 + s)*64 + d ] = f2bf((acc[i][j][r] + bsv)*0.125f);
        }
      }
    }
  }
}

// ---------------------------------------------------------------------------
// Kernel 3: fused attention per (n, 16-query tile).
// Phase 1: S = Q K^T, K d-blocked -> 256B-contiguous B-frag loads, batched 8
//          deep; transpose-write f16 scores to sS (xor-swizzled chunks)
// Phase 2: wave owns 4 rows interleaved; paired b32 LDS reads; row-max only;
//          FIXED 13-iter branchless bisection on [vmax-16, vmax];
//          probs (f16) overwrite scores in place
// Phase 3: O = P V in f16 MFMA, V direct from L2 (k-blocked layout)
// LDS 32KB, 2 barriers.
// ---------------------------------------------------------------------------
__global__ __launch_bounds__(256) void attn_k(const ushort_t* ws_q, const ushort_t* ws_k,
     const ushort_t* ws_v, const ushort_t* maskp, ushort_t* attn){
  __shared__ ushort_t sS[16*1024];         // 32KB: scores f16 -> probs f16, in place

  int tid = threadIdx.x, lane = tid&63, w = tid>>6;
  int r16 = lane&15, quad = lane>>4;
  // XCD swizzle: each XCD gets a contiguous span of 8 heads
  int gid = blockIdx.x;
  int n  = (gid & 7)*8 + ((gid >> 3) >> 6);
  int q0 = ((gid >> 3) & 63) * 16;
  const ushort_t* Qn = ws_q + (size_t)n*SEQ*DK;
  const ushort_t* Kn = ws_k + (size_t)n*SEQ*DK;   // d-blocked [g][key][8]
  const ushort_t* Vb = ws_v + (size_t)n*SEQ*DK;   // k-blocked [sb][d][ss], f16

  unsigned rmask = (unsigned)maskp[lane];  // bit m <-> column (m>>1)*128 + lane*2 + (m&1)

  // Q A-frags (row m = r16, k = t*32 + quad*8 + j)
  bf16x8 aQ[2];
  #pragma unroll
  for (int t=0;t<2;t++)
    aQ[t] = frag16(Qn + (size_t)(q0 + r16)*64 + t*32 + quad*8);

  const f32x4 zero = {0.f,0.f,0.f,0.f};

  // ---- Phase 1: scores; K B-frags contiguous (g = t*4+quad) ----
  #pragma unroll
  for (int half=0; half<2; half++){
    f32x4 acc[8];
    #pragma unroll
    for (int i=0;i<8;i++) acc[i] = zero;
    #pragma unroll
    for (int grp=0; grp<2; grp++){
      int c = half*2 + grp;
      bf16x8 bF[8];
      #pragma unroll
      for (int u=0;u<4;u++){
        int key = c*256 + w*64 + u*16 + r16;
        bF[u*2+0] = frag16(Kn + ((size_t)(quad    )*1024 + key)*8);
        bF[u*2+1] = frag16(Kn + ((size_t)(4 + quad)*1024 + key)*8);
      }
      #pragma unroll
      for (int u=0;u<4;u++){
        int t8 = grp*4 + u;
        acc[t8] = __builtin_amdgcn_mfma_f32_16x16x32_bf16(aQ[0], bF[u*2+0], acc[t8], 0,0,0);
        acc[t8] = __builtin_amdgcn_mfma_f32_16x16x32_bf16(aQ[1], bF[u*2+1], acc[t8], 0,0,0);
      }
    }
    // transpose-write as f16: element (row,col) at row*1024 + ((col>>3)^(row&7))*8 + (col&7)
    #pragma unroll
    for (int grp=0; grp<2; grp++)
      #pragma unroll
      for (int u=0;u<4;u++){
        int c = half*2 + grp;
        int col = c*256 + w*64 + u*16 + r16;
        int c0 = col>>3, c7 = col&7;
        #pragma unroll
        for (int r=0;r<4;r++){
          int row = quad*4 + r;
          sS[row*1024 + ((c0 ^ (row&7))*8) + c7] = f2h(acc[grp*4+u][r]);
        }
      }
  }
  __syncthreads();

  // ---- Phase 2: wave w owns rows 4w..4w+3, interleaved ----
  float v[4][16];
  float vmax[4];
  #pragma unroll
  for (int r=0;r<4;r++){
    int row = w*4 + r, rs = row & 7;
    float m = -3.0e38f;
    #pragma unroll
    for (int j=0;j<8;j++){
      int chunk = j*16 + (lane>>2);
      unsigned pr = *(const unsigned*)&sS[row*1024 + (chunk ^ rs)*8 + (lane&3)*2];
      float a = h2f((ushort_t)(pr & 0xffffu));
      float b = h2f((ushort_t)(pr >> 16));
      v[r][2*j]   = a;
      v[r][2*j+1] = b;
      m = fmaxf(m, fmaxf(a, b));
    }
    vmax[r] = m;
  }
  #pragma unroll
  for (int off=32; off>=1; off>>=1)
    #pragma unroll
    for (int r=0;r<4;r++) vmax[r] = fmaxf(vmax[r], __shfl_xor(vmax[r], off));

  // fixed 13-iter branchless bisection on [vmax-16, vmax] (res 0.002 ~ f16 ulp;
  // elements below vmax-16 have p < 1.1e-7 -> selection irrelevant)
  float lo[4], hi[4];
  #pragma unroll
  for (int r=0;r<4;r++){ hi[r] = vmax[r]; lo[r] = vmax[r] - 16.0f; }
  #pragma unroll 1
  for (int it=0; it<13; it++){
    #pragma unroll
    for (int r=0;r<4;r++){
      float mid = 0.5f*(lo[r]+hi[r]);
      int cnt = 0;
      #pragma unroll
      for (int m2=0;m2<16;m2++)
        cnt += __popcll(__ballot(v[r][m2] >= mid));
      bool ge = (cnt >= TOPK_N);
      lo[r] = ge ? mid : lo[r];
      hi[r] = ge ? hi[r] : mid;
    }
  }
  // exp + scale (probs overwrite v), then row-sum
  float ls[4];
  #pragma unroll
  for (int r=0;r<4;r++){
    float thr = lo[r], s = 0.f;
    #pragma unroll
    for (int m2=0;m2<16;m2++){
      bool sel = (v[r][m2] >= thr) || ((rmask >> m2) & 1u);
      float e = __expf(v[r][m2] - vmax[r]);
      e = sel ? e*RSCALE : e;
      v[r][m2] = e; s += e;
    }
    ls[r] = s;
  }
  #pragma unroll
  for (int off=32; off>=1; off>>=1)
    #pragma unroll
    for (int r=0;r<4;r++) ls[r] += __shfl_xor(ls[r], off);
  #pragma unroll
  for (int r=0;r<4;r++){
    int row = w*4 + r, rs = row & 7;
    float rinv = 1.0f / ls[r];
    #pragma unroll
    for (int j=0;j<8;j++){
      int chunk = j*16 + (lane>>2);
      unsigned u = (unsigned)f2h(v[r][2*j]*rinv) | ((unsigned)f2h(v[r][2*j+1]*rinv) << 16);
      *(unsigned*)&sS[row*1024 + (chunk ^ rs)*8 + (lane&3)*2] = u;
    }
  }
  __syncthreads();

  // ---- Phase 3: O = P V (f16 MFMA), V direct from L2, batched 4 ----
  f32x4 oa0 = zero, oa1 = zero;
  #pragma unroll
  for (int kb2=0; kb2<8; kb2++){
    f16x8v bV[4], aP[4];
    #pragma unroll
    for (int u=0;u<4;u++){
      int g8 = (kb2*4 + u)*4 + quad;
      bV[u] = frag16h(Vb + ((size_t)g8*64 + w*16 + r16)*8);
      aP[u] = frag16h(sS + r16*1024 + (g8 ^ (r16&7))*8);
    }
    #pragma unroll
    for (int u=0;u<4;u++){
      if (u&1) oa1 = __builtin_amdgcn_mfma_f32_16x16x32_f16(aP[u], bV[u], oa1, 0,0,0);
      else     oa0 = __builtin_amdgcn_mfma_f32_16x16x32_f16(aP[u], bV[u], oa0, 0,0,0);
    }
  }
  f32x4 oacc = oa0 + oa1;

  // epilogue: merged-head layout attn[b][s][h*64 + d], bf16
  int h = n >> 3, b = n & 7;
  #pragma unroll
  for (int r=0;r<4;r++){
    int s = q0 + quad*4 + r;
    attn[ ((size_t)(b*1024 + s))*512 + h*64 + w*16 + r16 ] = f2bf(oacc[r]);
  }
}

// ---------------------------------------------------------------------------
extern "C" void kernel_launch(void* const* d_in, const int* in_sizes, int n_in,
                              void* d_out, int out_size, void* d_ws, size_t ws_size,
                              hipStream_t stream){
  const float* Qx  = (const float*)d_in[0];
  const float* KVx = (const float*)d_in[1];
  const float* Wq  = (const float*)d_in[2];
  const float* bq  = (const float*)d_in[3];
  const float* Wk  = (const float*)d_in[4];
  const float* bk  = (const float*)d_in[5];
  const float* Wv  = (const float*)d_in[6];
  const float* bv  = (const float*)d_in[7];
  const float* Wo  = (const float*)d_in[8];
  const float* bo  = (const float*)d_in[9];
  const int* ridx  = (const int*)d_in[10];
  int nrand = in_sizes[10];
  ushort_t* ws = (ushort_t*)d_ws;
  float* dout = (float*)d_out;

  mask_k<<<1, 128, 0, stream>>>(ridx, nrand, ws + OFF_MASK);
  cvt_k<<<dim3(2048,2), 256, 0, stream>>>(Qx, KVx, ws);
  wtrans_k<<<dim3(8,8,4), 256, 0, stream>>>(Wq, Wk, Wv, Wo, ws + OFF_WT);
  gemm_k<<<dim3(4,64,3), 256, 0, stream>>>(ws, bq, bk, bv, bo, dout, 0);
  attn_k<<<4096, 256, 0, stream>>>(ws+OFF_Q, ws+OFF_K, ws+OFF_V, ws+OFF_MASK, ws+OFF_A);
  gemm_k<<<dim3(4,64,1), 256, 0, stream>>>(ws, bq, bk, bv, bo, dout, 3);
}

// Round 7
// 248.040 us; speedup vs baseline: 1.5260x; 1.0645x over previous
//
#include <hip/hip_runtime.h>
#include <stdint.h>

typedef unsigned short ushort_t;
typedef __bf16 bf16x8 __attribute__((ext_vector_type(8)));
typedef _Float16 f16x8v __attribute__((ext_vector_type(8)));
typedef __fp16 fp16x2 __attribute__((ext_vector_type(2)));
typedef float f32x4 __attribute__((ext_vector_type(4)));

#define SEQ   1024
#define DK    64
#define TOPK_N 51
#define RSCALE 1.2f

// workspace element offsets (ushort elements). A aliases QX (QX dead after gemm modes 0-2).
#define OFF_WT  0                          // 4 * 512*512
#define OFF_Q   (4*512*512)                // Qs[nh][s][64], scaled 1/8
#define OFF_K   (OFF_Q  + 64*1024*64)      // K d-blocked: [nh][d>>3][key][d&7]
#define OFF_V   (OFF_K  + 64*1024*64)      // V f16: [nh][s>>2][d][s&3]
#define OFF_QX  (OFF_V  + 64*1024*64)      // 8192*512 bf16 copy of Query_x
#define OFF_KVX (OFF_QX + 8192*512)        // 8192*512 bf16 copy of KeyandValue_x
#define OFF_MASK (OFF_KVX + 8192*512)      // 64 u16 mask table (col-chunk keyed)
#define OFF_A   OFF_QX                     // attn output (bf16), reuses QX

static __device__ __forceinline__ ushort_t f2bf(float f){
  union { float f; unsigned u; } x; x.f = f;
  unsigned r = x.u + 0x7FFFu + ((x.u >> 16) & 1u);   // RNE
  return (ushort_t)(r >> 16);
}
static __device__ __forceinline__ ushort_t f2h(float f){
  union { _Float16 h; ushort_t u; } x; x.h = (_Float16)f; return x.u;
}
static __device__ __forceinline__ float h2f(ushort_t u){
  union { ushort_t u; _Float16 h; } x; x.u = u; return (float)x.h;
}
static __device__ __forceinline__ unsigned pk2(float a, float b){
  union { fp16x2 h; unsigned u; } x;
  x.h = __builtin_amdgcn_cvt_pkrtz(a, b);
  return x.u;
}
static __device__ __forceinline__ bf16x8 frag16(const ushort_t* p){
  union { uint4 u; bf16x8 b; } x; x.u = *(const uint4*)p; return x.b;
}
static __device__ __forceinline__ f16x8v frag16h(const ushort_t* p){
  union { uint4 u; f16x8v h; } x; x.u = *(const uint4*)p; return x.h;
}
// async global->LDS, 16B per lane; lds base wave-uniform (HW adds lane*16)
static __device__ __forceinline__ void gll16(const ushort_t* g, ushort_t* lds){
  __builtin_amdgcn_global_load_lds((const __attribute__((address_space(1))) unsigned*)g,
                                   (__attribute__((address_space(3))) unsigned*)lds,
                                   16, 0, 0);
}

// ---------------------------------------------------------------------------
// Kernel 0 (fused prep): blocks 0..4095 cvt f32->bf16; 4096..4351 weight
// convert+transpose; 4352 rand-column mask table.
// mask table: mt[c] (c=0..63): bit e <-> col c*8+e; bit 8+e <-> col 512+c*8+e
// ---------------------------------------------------------------------------
__global__ __launch_bounds__(256) void prep_k(const float* qx, const float* kvx,
    const float* Wq, const float* Wk, const float* Wv, const float* Wo,
    const int* ridx, int nrand, ushort_t* ws){
  __shared__ ushort_t t[64][72];
  __shared__ unsigned wds[64];
  int bid = blockIdx.x, tid = threadIdx.x;

  if (bid < 4096){
    const float* src = (bid >= 2048) ? kvx : qx;
    ushort_t* dst = ws + ((bid >= 2048) ? OFF_KVX : OFF_QX);
    int i = ((bid & 2047)*256 + tid) * 8;
    float4 a = *(const float4*)(src + i);
    float4 b = *(const float4*)(src + i + 4);
    union { ushort_t s[8]; uint4 u; } p;
    p.s[0]=f2bf(a.x); p.s[1]=f2bf(a.y); p.s[2]=f2bf(a.z); p.s[3]=f2bf(a.w);
    p.s[4]=f2bf(b.x); p.s[5]=f2bf(b.y); p.s[6]=f2bf(b.z); p.s[7]=f2bf(b.w);
    *(uint4*)(dst + i) = p.u;
  } else if (bid < 4352){
    int rb = bid - 4096;
    int z = rb >> 6, rem = rb & 63;
    const float* W = z==0?Wq: z==1?Wk: z==2?Wv: Wo;
    ushort_t* O = ws + OFF_WT + (size_t)z*512*512;
    int kt = (rem >> 3)*64, nt = (rem & 7)*64;
    int r0 = tid>>3, c8 = (tid&7)*8;
    #pragma unroll
    for (int p=0;p<2;p++){
      int r = p*32 + r0;
      float4 a = *(const float4*)&W[(size_t)(kt+r)*512 + nt + c8];
      float4 b = *(const float4*)&W[(size_t)(kt+r)*512 + nt + c8 + 4];
      t[r][c8+0]=f2bf(a.x); t[r][c8+1]=f2bf(a.y); t[r][c8+2]=f2bf(a.z); t[r][c8+3]=f2bf(a.w);
      t[r][c8+4]=f2bf(b.x); t[r][c8+5]=f2bf(b.y); t[r][c8+6]=f2bf(b.z); t[r][c8+7]=f2bf(b.w);
    }
    __syncthreads();
    #pragma unroll
    for (int p=0;p<2;p++){
      int r = p*32 + r0;
      union { ushort_t s[8]; uint4 u; } tmp;
      #pragma unroll
      for (int j=0;j<8;j++) tmp.s[j] = t[c8+j][r];
      *(uint4*)&O[(size_t)(nt+r)*512 + kt + c8] = tmp.u;
    }
  } else {
    if (tid < 64) wds[tid] = 0;
    __syncthreads();
    for (int i = tid; i < nrand; i += 256){
      int col = ridx[i];
      atomicOr(&wds[(col >> 3) & 63], 1u << (((col >> 9) << 3) | (col & 7)));
    }
    __syncthreads();
    if (tid < 64) (ws + OFF_MASK)[tid] = (ushort_t)wds[tid];
  }
}

// ---------------------------------------------------------------------------
// Kernel 2/4: 128x128-tile bf16 GEMM  Y = X*W + b  (W transposed, bf16 in ws).
// mode 0: Q proj (X=QXb)  -> Qs[n][s][64], scaled 1/8 (=1/sqrt(dk))
// mode 1: K proj (X=KVXb) -> Kd[n][d>>3][key][d&7]  (d-blocked for QK^T B-frags)
// mode 2: V proj (X=KVXb) -> Vb[n][s>>2][d][s&3] F16 (coalesced b64 stores)
// mode 3: out proj (X=A)  -> d_out [8192][512] f32
// ---------------------------------------------------------------------------
__global__ __launch_bounds__(256) void gemm_k(ushort_t* ws, const float* bq, const float* bk,
    const float* bv, const float* bo, float* dout, int base_mode){
  int mode = base_mode + blockIdx.z;
  const ushort_t* X  = (mode==0)? ws+OFF_QX : (mode==3)? ws+OFF_A : ws+OFF_KVX;
  const ushort_t* WT = ws + OFF_WT + (size_t)mode*(512*512);
  const float* bias  = (mode==0)?bq:(mode==1)?bk:(mode==2)?bv:bo;
  ushort_t* out = (mode==0)? ws+OFF_Q : (mode==1)? ws+OFF_K : ws+OFF_V;

  __shared__ ushort_t sA[128*64];
  __shared__ ushort_t sB[128*64];
  int tid = threadIdx.x, lane = tid & 63, w = tid >> 6;
  int wm = w & 1, wn = w >> 1;
  int m0 = blockIdx.y * 128, n0 = blockIdx.x * 128;
  int r16 = lane & 15, quad = lane >> 4;
  int srow = lane >> 3, schunk = lane & 7;   // staging: 8 rows x 8 chunks of 16B

  const f32x4 zero = {0.f,0.f,0.f,0.f};
  f32x4 acc[4][4];
  #pragma unroll
  for (int i=0;i<4;i++)
    #pragma unroll
    for (int j=0;j<4;j++) acc[i][j] = zero;

  for (int kb = 0; kb < 8; kb++){
    int k0 = kb*64;
    #pragma unroll
    for (int i=0;i<4;i++){
      int rb = w*32 + i*8;                 // rb % 8 == 0
      int gch = schunk ^ srow;             // xor-swizzle: slot s holds chunk s^(row&7)
      gll16(X  + (size_t)(m0+rb+srow)*512 + k0 + gch*8, sA + rb*64);
      gll16(WT + (size_t)(n0+rb+srow)*512 + k0 + gch*8, sB + rb*64);
    }
    __syncthreads();
    #pragma unroll
    for (int t=0;t<2;t++){
      bf16x8 aF[4], bF[4];
      #pragma unroll
      for (int i=0;i<4;i++){
        int row = wm*64 + i*16 + r16;
        aF[i] = frag16(sA + row*64 + ((t*4 + quad) ^ (row & 7))*8);
      }
      #pragma unroll
      for (int j=0;j<4;j++){
        int row = wn*64 + j*16 + r16;
        bF[j] = frag16(sB + row*64 + ((t*4 + quad) ^ (row & 7))*8);
      }
      #pragma unroll
      for (int i=0;i<4;i++)
        #pragma unroll
        for (int j=0;j<4;j++)
          acc[i][j] = __builtin_amdgcn_mfma_f32_16x16x32_bf16(aF[i], bF[j], acc[i][j], 0,0,0);
    }
    __syncthreads();
  }

  // epilogue
  #pragma unroll
  for (int i=0;i<4;i++){
    int rowbase = m0 + wm*64 + i*16 + quad*4;     // 4 consecutive rows, rowbase%4==0
    #pragma unroll
    for (int j=0;j<4;j++){
      int col = n0 + wn*64 + j*16 + r16;
      float bsv = bias[col];
      if (mode == 3){
        #pragma unroll
        for (int r=0;r<4;r++)
          dout[(size_t)(rowbase+r)*512 + col] = acc[i][j][r] + bsv;
      } else if (mode == 2){
        int b = rowbase >> 10, s = rowbase & 1023;
        int h = col >> 6, d = col & 63;
        int nh = h*8 + b;
        int sb2 = s >> 2;                         // s%4==0 -> r is s&3
        union { ushort_t sh[4]; uint2 u2; } pk;   // F16 V
        #pragma unroll
        for (int r=0;r<4;r++) pk.sh[r] = f2h(acc[i][j][r] + bsv);
        *(uint2*)&out[ (((size_t)nh*256 + sb2)*64 + d)*4 ] = pk.u2;
      } else if (mode == 1){
        int b = rowbase >> 10;
        int h = col >> 6, d = col & 63;
        int nh = h*8 + b;
        // Kd[nh][d>>3][key][d&7]
        size_t base = (size_t)nh*65536 + (size_t)(d>>3)*8192 + (d&7);
        #pragma unroll
        for (int r=0;r<4;r++){
          int s = (rowbase + r) & 1023;
          out[ base + (size_t)s*8 ] = f2bf(acc[i][j][r] + bsv);
        }
      } else {
        int h = col >> 6, d = col & 63;
        #pragma unroll
        for (int r=0;r<4;r++){
          int row = rowbase + r;
          int b = row >> 10, s = row & 1023;
          int nh = h*8 + b;
          out[ ((size_t)nh*1024 + s)*64 + d ] = f2bf((acc[i][j][r] + bsv)*0.125f);
        }
      }
    }
  }
}

// ---------------------------------------------------------------------------
// Kernel 3: fused attention per (n, 16-query tile).
// Phase 1: S = Q K^T, K d-blocked (contiguous B-frags from L2); transpose-
//          write f16 scores to sS (chunk c of row at phys (c^(row&7)))
// Phase 2: wave owns rows 4w..4w+3 interleaved. Lane reads phys chunks
//          lane^rs and 64+(lane^rs) as TWO b128 -> always owns logical cols
//          lane*8+e and 512+lane*8+e (row-independent -> one mask u16/lane).
//          12-iter branchless bisection on [vmax-8, vmax]; exp; pkrtz pack;
//          2 b128 writeback in place.
// Phase 3: O = P V f16 MFMA; V [s>>2][d][s&3] -> 2x dwordx2 per frag from L2
// LDS 32KB, 2 barriers.
// ---------------------------------------------------------------------------
__global__ __launch_bounds__(256, 5) void attn_k(const ushort_t* ws_q, const ushort_t* ws_k,
     const ushort_t* ws_v, const ushort_t* maskp, ushort_t* attn){
  __shared__ __align__(16) ushort_t sS[16*1024]; // 32KB: scores f16 -> probs f16

  int tid = threadIdx.x, lane = tid&63, w = tid>>6;
  int r16 = lane&15, quad = lane>>4;
  // XCD swizzle: each XCD gets a contiguous span of 8 heads
  int gid = blockIdx.x;
  int n  = (gid & 7)*8 + ((gid >> 3) >> 6);
  int q0 = ((gid >> 3) & 63) * 16;
  const ushort_t* Qn = ws_q + (size_t)n*SEQ*DK;
  const ushort_t* Kn = ws_k + (size_t)n*SEQ*DK;   // d-blocked [g][key][8]
  const ushort_t* Vb = ws_v + (size_t)n*SEQ*DK;   // [s>>2][d][s&3], f16

  unsigned rmask = (unsigned)maskp[lane];  // bit e<->col lane*8+e; bit 8+e<->col 512+lane*8+e

  // Q A-frags (row m = r16, k = t*32 + quad*8 + j)
  bf16x8 aQ[2];
  #pragma unroll
  for (int t=0;t<2;t++)
    aQ[t] = frag16(Qn + (size_t)(q0 + r16)*64 + t*32 + quad*8);

  const f32x4 zero = {0.f,0.f,0.f,0.f};

  // ---- Phase 1: scores; K B-frags contiguous (g = t*4+quad) ----
  #pragma unroll
  for (int half=0; half<2; half++){
    f32x4 acc[8];
    #pragma unroll
    for (int i=0;i<8;i++) acc[i] = zero;
    #pragma unroll
    for (int grp=0; grp<2; grp++){
      int c = half*2 + grp;
      bf16x8 bF[8];
      #pragma unroll
      for (int u=0;u<4;u++){
        int key = c*256 + w*64 + u*16 + r16;
        bF[u*2+0] = frag16(Kn + ((size_t)(quad    )*1024 + key)*8);
        bF[u*2+1] = frag16(Kn + ((size_t)(4 + quad)*1024 + key)*8);
      }
      #pragma unroll
      for (int u=0;u<4;u++){
        int t8 = grp*4 + u;
        acc[t8] = __builtin_amdgcn_mfma_f32_16x16x32_bf16(aQ[0], bF[u*2+0], acc[t8], 0,0,0);
        acc[t8] = __builtin_amdgcn_mfma_f32_16x16x32_bf16(aQ[1], bF[u*2+1], acc[t8], 0,0,0);
      }
    }
    // transpose-write as f16: element (row,col) at row*1024 + ((col>>3)^(row&7))*8 + (col&7)
    #pragma unroll
    for (int grp=0; grp<2; grp++)
      #pragma unroll
      for (int u=0;u<4;u++){
        int c = half*2 + grp;
        int col = c*256 + w*64 + u*16 + r16;
        int c0 = col>>3, c7 = col&7;
        #pragma unroll
        for (int r=0;r<4;r++){
          int row = quad*4 + r;
          sS[row*1024 + ((c0 ^ (row&7))*8) + c7] = f2h(acc[grp*4+u][r]);
        }
      }
  }
  __syncthreads();

  // ---- Phase 2: wave w owns rows 4w..4w+3, interleaved, b128 access ----
  float v[4][16];
  float vmax[4];
  #pragma unroll
  for (int r=0;r<4;r++){
    int row = w*4 + r, rs = row & 7;
    const ushort_t* bp = sS + row*1024 + ((lane ^ rs) * 8);
    uint4 lo4 = *(const uint4*)bp;
    uint4 hi4 = *(const uint4*)(bp + 512);
    unsigned wl[8] = {lo4.x, lo4.y, lo4.z, lo4.w, hi4.x, hi4.y, hi4.z, hi4.w};
    float m = -3.0e38f;
    #pragma unroll
    for (int k=0;k<8;k++){
      float a = h2f((ushort_t)(wl[k] & 0xffffu));
      float b = h2f((ushort_t)(wl[k] >> 16));
      v[r][2*k] = a; v[r][2*k+1] = b;
      m = fmaxf(m, fmaxf(a, b));
    }
    vmax[r] = m;
  }
  #pragma unroll
  for (int off=32; off>=1; off>>=1)
    #pragma unroll
    for (int r=0;r<4;r++) vmax[r] = fmaxf(vmax[r], __shfl_xor(vmax[r], off));

  // 12-iter branchless bisection on [vmax-8, vmax] (res 0.002 ~ f16 ulp;
  // elements below vmax-8 have p < 3.4e-4 and thr-vmax is ~0.3 typically)
  float blo[4], bhi[4];
  #pragma unroll
  for (int r=0;r<4;r++){ bhi[r] = vmax[r]; blo[r] = vmax[r] - 8.0f; }
  #pragma unroll 1
  for (int it=0; it<12; it++){
    #pragma unroll
    for (int r=0;r<4;r++){
      float mid = 0.5f*(blo[r]+bhi[r]);
      int cnt = 0;
      #pragma unroll
      for (int j=0;j<16;j++)
        cnt += __popcll(__ballot(v[r][j] >= mid));
      bool ge = (cnt >= TOPK_N);
      blo[r] = ge ? mid : blo[r];
      bhi[r] = ge ? bhi[r] : mid;
    }
  }
  // exp + scale (probs overwrite v), then row-sum
  float ls[4];
  #pragma unroll
  for (int r=0;r<4;r++){
    float thr = blo[r], s = 0.f;
    #pragma unroll
    for (int j=0;j<16;j++){
      bool sel = (v[r][j] >= thr) || ((rmask >> j) & 1u);
      float e = __expf(v[r][j] - vmax[r]);
      e = sel ? e*RSCALE : e;
      v[r][j] = e; s += e;
    }
    ls[r] = s;
  }
  #pragma unroll
  for (int off=32; off>=1; off>>=1)
    #pragma unroll
    for (int r=0;r<4;r++) ls[r] += __shfl_xor(ls[r], off);
  #pragma unroll
  for (int r=0;r<4;r++){
    int row = w*4 + r, rs = row & 7;
    float rinv = 1.0f / ls[r];
    ushort_t* bp = sS + row*1024 + ((lane ^ rs) * 8);
    uint4 o0, o1;
    o0.x = pk2(v[r][0]*rinv,  v[r][1]*rinv);
    o0.y = pk2(v[r][2]*rinv,  v[r][3]*rinv);
    o0.z = pk2(v[r][4]*rinv,  v[r][5]*rinv);
    o0.w = pk2(v[r][6]*rinv,  v[r][7]*rinv);
    o1.x = pk2(v[r][8]*rinv,  v[r][9]*rinv);
    o1.y = pk2(v[r][10]*rinv, v[r][11]*rinv);
    o1.z = pk2(v[r][12]*rinv, v[r][13]*rinv);
    o1.w = pk2(v[r][14]*rinv, v[r][15]*rinv);
    *(uint4*)bp = o0;
    *(uint4*)(bp + 512) = o1;
  }
  __syncthreads();

  // ---- Phase 3: O = P V (f16 MFMA), V 2x dwordx2 per frag, batched 4 ----
  f32x4 oa0 = zero, oa1 = zero;
  int dd = w*16 + r16;
  #pragma unroll
  for (int kb2=0; kb2<8; kb2++){
    f16x8v bV[4], aP[4];
    #pragma unroll
    for (int u=0;u<4;u++){
      int g8 = (kb2*4 + u)*4 + quad;
      size_t vb = ((size_t)(g8*2)*64 + dd)*4;
      uint2 l0 = *(const uint2*)&Vb[vb];         // k = g8*8 .. +3
      uint2 l1 = *(const uint2*)&Vb[vb + 256];   // k = g8*8+4 .. +7
      union { uint4 u4; f16x8v h; } bb;
      bb.u4 = make_uint4(l0.x, l0.y, l1.x, l1.y);
      bV[u] = bb.h;
      aP[u] = frag16h(sS + r16*1024 + (g8 ^ (r16&7))*8);
    }
    #pragma unroll
    for (int u=0;u<4;u++){
      if (u&1) oa1 = __builtin_amdgcn_mfma_f32_16x16x32_f16(aP[u], bV[u], oa1, 0,0,0);
      else     oa0 = __builtin_amdgcn_mfma_f32_16x16x32_f16(aP[u], bV[u], oa0, 0,0,0);
    }
  }
  f32x4 oacc = oa0 + oa1;

  // epilogue: merged-head layout attn[b][s][h*64 + d], bf16
  int h = n >> 3, b = n & 7;
  #pragma unroll
  for (int r=0;r<4;r++){
    int s = q0 + quad*4 + r;
    attn[ ((size_t)(b*1024 + s))*512 + h*64 + w*16 + r16 ] = f2bf(oacc[r]);
  }
}

// ---------------------------------------------------------------------------
extern "C" void kernel_launch(void* const* d_in, const int* in_sizes, int n_in,
                              void* d_out, int out_size, void* d_ws, size_t ws_size,
                              hipStream_t stream){
  const float* Qx  = (const float*)d_in[0];
  const float* KVx = (const float*)d_in[1];
  const float* Wq  = (const float*)d_in[2];
  const float* bq  = (const float*)d_in[3];
  const float* Wk  = (const float*)d_in[4];
  const float* bk  = (const float*)d_in[5];
  const float* Wv  = (const float*)d_in[6];
  const float* bv  = (const float*)d_in[7];
  const float* Wo  = (const float*)d_in[8];
  const float* bo  = (const float*)d_in[9];
  const int* ridx  = (const int*)d_in[10];
  int nrand = in_sizes[10];
  ushort_t* ws = (ushort_t*)d_ws;
  float* dout = (float*)d_out;

  prep_k<<<4353, 256, 0, stream>>>(Qx, KVx, Wq, Wk, Wv, Wo, ridx, nrand, ws);
  gemm_k<<<dim3(4,64,3), 256, 0, stream>>>(ws, bq, bk, bv, bo, dout, 0);
  attn_k<<<4096, 256, 0, stream>>>(ws+OFF_Q, ws+OFF_K, ws+OFF_V, ws+OFF_MASK, ws+OFF_A);
  gemm_k<<<dim3(4,64,1), 256, 0, stream>>>(ws, bq, bk, bv, bo, dout, 3);
}